// Round 18
// baseline (405.591 us; speedup 1.0000x reference)
//
#include <hip/hip_runtime.h>
#include <math.h>

#define TT 2048
#define BB 2
#define HH 16
#define DMODEL 1024
#define NREL 4095                      // 2*TT-1

typedef __attribute__((ext_vector_type(8)))  _Float16 half8;
typedef __attribute__((ext_vector_type(4)))  _Float16 half4;
typedef __attribute__((ext_vector_type(16))) float    f32x16;
typedef __attribute__((ext_vector_type(4)))  float    f32x4;
typedef __attribute__((ext_vector_type(4)))  int      int4v;

#define EXP2F(x) __builtin_amdgcn_exp2f(x)

__device__ __forceinline__ f32x16 zero16() {
    f32x16 v;
#pragma unroll
    for (int i = 0; i < 16; ++i) v[i] = 0.f;
    return v;
}

__device__ __forceinline__ f32x4 zero4() {
    f32x4 v; v[0] = v[1] = v[2] = v[3] = 0.f; return v;
}

__device__ __forceinline__ unsigned pkh(float a, float b) {
    union { _Float16 h[2]; unsigned u; } x;
    x.h[0] = (_Float16)a; x.h[1] = (_Float16)b;
    return x.u;
}

// async global->LDS, 16B per lane; LDS dest = wave-uniform base + lane*16
__device__ __forceinline__ void gload16(const void* g, void* l) {
    __builtin_amdgcn_global_load_lds(
        (const __attribute__((address_space(1))) void*)g,
        (__attribute__((address_space(3))) void*)l, 16, 0, 0);
}

// ---------------- bucket (exact-integer replication of reference log math) ---
__device__ __forceinline__ int rel_bucket(int rel) {
    int base = rel > 0 ? 16 : 0;
    int r = rel < 0 ? -rel : rel;
    int lb;
    if (r < 8)       lb = r;
    else if (r < 12) lb = 8;
    else if (r < 16) lb = 9;
    else if (r < 23) lb = 10;
    else if (r < 32) lb = 11;
    else if (r < 46) lb = 12;
    else if (r < 64) lb = 13;
    else if (r < 91) lb = 14;
    else             lb = 15;
    return base + lb;
}

// ---------------- fused prep: bias_table | wtrans | maskpack -----------------
__global__ __launch_bounds__(256) void prep_kernel(
    const int* __restrict__ mask,
    const float* __restrict__ W0, const float* __restrict__ W1,
    const float* __restrict__ W2, const float* __restrict__ W3,
    const float* __restrict__ rel_bias,
    _Float16* __restrict__ WT,
    float* __restrict__ btable, unsigned* __restrict__ mb)
{
    __shared__ float t[64][65];
    int bid = blockIdx.x, tid = threadIdx.x;
    if (bid < 256) {
        int idx = bid * 256 + tid;
        if (idx < HH * NREL) {
            int h = idx / NREL, ri = idx % NREL;
            btable[idx] = rel_bias[rel_bucket(ri - (TT - 1)) * HH + h];
        }
    } else if (bid < 1280) {
        int zz = (bid - 256) >> 8, inner = (bid - 256) & 255;
        const float* src = zz == 0 ? W0 : zz == 1 ? W1 : zz == 2 ? W2 : W3;
        _Float16* dst = WT + (size_t)zz * DMODEL * DMODEL;
        int k0 = (inner >> 4) * 64, n0 = (inner & 15) * 64;
        int r = tid >> 4, c4 = (tid & 15) * 4;
#pragma unroll
        for (int i = 0; i < 4; ++i) {
            float4 vv = *(const float4*)(src + (size_t)(k0 + r + 16 * i) * DMODEL + n0 + c4);
            t[r + 16 * i][c4] = vv.x; t[r + 16 * i][c4 + 1] = vv.y;
            t[r + 16 * i][c4 + 2] = vv.z; t[r + 16 * i][c4 + 3] = vv.w;
        }
        __syncthreads();
        int rn = tid >> 2, ck = (tid & 3) * 16;
        half8 h0, h1;
#pragma unroll
        for (int j = 0; j < 8; ++j) h0[j] = (_Float16)t[ck + j][rn];
#pragma unroll
        for (int j = 0; j < 8; ++j) h1[j] = (_Float16)t[ck + 8 + j][rn];
        *(half8*)(dst + (size_t)(n0 + rn) * DMODEL + k0 + ck) = h0;
        *(half8*)(dst + (size_t)(n0 + rn) * DMODEL + k0 + ck + 8) = h1;
    } else {
        int g = (bid - 1280) * 256 + tid;
        int vv = mask[g];
        unsigned long long bal = __ballot(vv != 0);
        if ((g & 63) == 0) {
            int word = g >> 5;
            mb[word]     = (unsigned)bal;
            mb[word + 1] = (unsigned)(bal >> 32);
        }
    }
}

// ---------------- fused projection MFMA GEMM (z: 0=q,1=k,2=v) ----------------
// A read directly from f32 inputs with in-register cvt; B via gload_lds.
__global__ __launch_bounds__(256) void gemm_proj3(
    const float* __restrict__ qf32, const float* __restrict__ kf32,
    const float* __restrict__ vf32, const _Float16* __restrict__ WT,
    _Float16* __restrict__ qhf, _Float16* __restrict__ khf,
    _Float16* __restrict__ vtf, int zbase)
{
    __shared__ __align__(16) char lds[65536];   // 2 x {A [0,16K), B [16K,32K)}
    int z = zbase + blockIdx.z;
    const float* A = z == 0 ? qf32 : z == 1 ? kf32 : vf32;
    const _Float16* Bt = WT + (size_t)z * DMODEL * DMODEL;
    int bm = blockIdx.x * 128, bn = blockIdx.y * 128;
    int tid = threadIdx.x;
    int wv = tid >> 6, lane = tid & 63, hi = lane >> 5;
    int lo = lane & 31;
    int wr = wv >> 1, wc = wv & 1;
    int srow = wv * 32 + (lane >> 3);
    int scol = (lane & 7) * 8;
    const float*    Abase = A  + (size_t)(bm + srow) * DMODEL + scol;
    const _Float16* Bbase = Bt + (size_t)(bn + srow) * DMODEL + scol;
    int awoff = wv * 4096 + (lane >> 3) * 128 + (lane & 7) * 16;

    f32x16 acc[2][2];
    acc[0][0] = zero16(); acc[0][1] = zero16();
    acc[1][0] = zero16(); acc[1][1] = zero16();

    float4 ra[8];
    auto loadA = [&](int kt) {
#pragma unroll
        for (int t = 0; t < 4; ++t) {
            ra[2 * t]     = *(const float4*)(Abase + (size_t)t * 8 * DMODEL + kt * 64);
            ra[2 * t + 1] = *(const float4*)(Abase + (size_t)t * 8 * DMODEL + kt * 64 + 4);
        }
    };
    auto gloadB = [&](int buf, int kt) {
#pragma unroll
        for (int t = 0; t < 4; ++t)
            gload16(Bbase + (size_t)t * 8 * DMODEL + kt * 64, lds + buf + 16384 + wv * 4096 + t * 1024);
    };
    auto writeA = [&](int buf) {
#pragma unroll
        for (int t = 0; t < 4; ++t) {
            float4 v0 = ra[2 * t], v1 = ra[2 * t + 1];
            half8 h = {(_Float16)v0.x, (_Float16)v0.y, (_Float16)v0.z, (_Float16)v0.w,
                       (_Float16)v1.x, (_Float16)v1.y, (_Float16)v1.z, (_Float16)v1.w};
            *(half8*)(lds + buf + awoff + t * 1024) = h;
        }
    };
    auto compute = [&](int buf) {
#pragma unroll
        for (int kk = 0; kk < 4; ++kk) {
            int cs = 2 * kk + hi;
            half8 a[2], b[2];
#pragma unroll
            for (int i = 0; i < 2; ++i) {
                a[i] = *(const half8*)(lds + buf + (wr * 64 + i * 32 + lo) * 128 + cs * 16);
                b[i] = *(const half8*)(lds + buf + 16384 + (wc * 64 + i * 32 + lo) * 128 + cs * 16);
            }
            acc[0][0] = __builtin_amdgcn_mfma_f32_32x32x16_f16(a[0], b[0], acc[0][0], 0, 0, 0);
            acc[0][1] = __builtin_amdgcn_mfma_f32_32x32x16_f16(a[0], b[1], acc[0][1], 0, 0, 0);
            acc[1][0] = __builtin_amdgcn_mfma_f32_32x32x16_f16(a[1], b[0], acc[1][0], 0, 0, 0);
            acc[1][1] = __builtin_amdgcn_mfma_f32_32x32x16_f16(a[1], b[1], acc[1][1], 0, 0, 0);
        }
    };

    loadA(0); gloadB(0, 0); writeA(0);
    __syncthreads();
    for (int kt = 0; kt < 16; kt += 2) {
        loadA(kt + 1); gloadB(32768, kt + 1);
        compute(0);
        writeA(32768);
        __syncthreads();
        if (kt + 2 < 16) { loadA(kt + 2); gloadB(0, kt + 2); }
        compute(32768);
        if (kt + 2 < 16) writeA(0);
        __syncthreads();
    }

    if (z < 2) {
        _Float16* C = z == 0 ? qhf : khf;
#pragma unroll
        for (int j = 0; j < 2; ++j) {
            int n = bn + wc * 64 + j * 32 + lo;
            int h = n >> 6, d = n & 63;
#pragma unroll
            for (int i = 0; i < 2; ++i) {
                int mb2 = bm + wr * 64 + i * 32 + 4 * hi;
#pragma unroll
                for (int r = 0; r < 16; ++r) {
                    int m = mb2 + (r & 3) + 8 * (r >> 2);
                    int b = m >> 11, t = m & (TT - 1);
                    C[((size_t)(b * HH + h) * TT + t) * 64 + d] = (_Float16)acc[i][j][r];
                }
            }
        }
    } else {
#pragma unroll
        for (int j = 0; j < 2; ++j) {
            int n = bn + wc * 64 + j * 32 + lo;
            int h = n >> 6, d = n & 63;
#pragma unroll
            for (int i = 0; i < 2; ++i) {
                int mb2 = bm + wr * 64 + i * 32 + 4 * hi;
                int b = mb2 >> 11, tb = mb2 & (TT - 1);
#pragma unroll
                for (int r4 = 0; r4 < 4; ++r4) {
                    half4 hv = {(_Float16)acc[i][j][4 * r4 + 0], (_Float16)acc[i][j][4 * r4 + 1],
                                (_Float16)acc[i][j][4 * r4 + 2], (_Float16)acc[i][j][4 * r4 + 3]};
                    *(half4*)(vtf + ((size_t)(b * HH + h) * 64 + d) * TT + tb + 8 * r4) = hv;
                }
            }
        }
    }
}

// ---------------- MFMA flash attention: 16x16x32 frags, 16 q-rows/wave -------
// Small fragment set (~110 unified regs) -> ~4 waves/SIMD (2x the 32x32 path).
// Swapped S^T/O^T; Kc=64; log2-domain softmax; LDS bias.
// Layouts: A[row=l&15][k=(l>>4)*8+j]; B[k=(l>>4)*8+j][n=l&15];
// C/D: col=l&15, row=(l>>4)*4+reg (guide-verified).
__global__ __launch_bounds__(256) void attn_mfma16(
    const _Float16* __restrict__ qh, const _Float16* __restrict__ kh,
    const _Float16* __restrict__ vt, const unsigned* __restrict__ maskbits,
    const float* __restrict__ btable, _Float16* __restrict__ Oout)
{
    __shared__ float bias_lds[4096];
    int bid = blockIdx.x;
    int xcd = bid & 7, jj = bid >> 3;
    int qg = jj & 31, bh = xcd + 8 * (jj >> 5);
    int h = bh & 15, b = bh >> 4;
    int tid = threadIdx.x;
    int wv = tid >> 6, lane = tid & 63;
    int col = lane & 15, u = lane >> 4, u4 = u * 4;
    int q0 = (qg * 4 + wv) * 16;

    {   // stage this head's bias row into LDS, pre-scaled by log2(e)
        const float* bsrc = btable + h * NREL;
#pragma unroll
        for (int i = 0; i < 16; ++i) {
            int idx = i * 256 + tid;
            bias_lds[idx] = bsrc[idx < NREL ? idx : NREL - 1] * 1.44269504f;
        }
    }

    const size_t bhoff = (size_t)(b * HH + h);
    const _Float16* Q = qh + (bhoff * TT + q0) * 64;
    const _Float16* K = kh + bhoff * TT * 64;
    const _Float16* V = vt + bhoff * 64 * TT;

    half8 qf[2];
    qf[0] = *(const half8*)(Q + (size_t)col * 64 + u * 8);
    qf[1] = *(const half8*)(Q + (size_t)col * 64 + 32 + u * 8);

    const int bofs = (TT - 1) - (q0 + col) + u4;
    const unsigned* mw = maskbits + ((size_t)b * TT + q0 + col) * 64;
    const float SC = 0.125f * 1.44269504f;

    f32x4 acco[4];
    acco[0] = zero4(); acco[1] = zero4(); acco[2] = zero4(); acco[3] = zero4();
    float m = -INFINITY, l = 0.f;

    __syncthreads();   // bias_lds ready

    for (int kt = 0; kt < 32; ++kt) {
        int k0 = kt * 64;
        unsigned wm0 = mw[2 * kt], wm1 = mw[2 * kt + 1];

        // ---- QK^T: 4 key-groups x 2 dim-frags (8 MFMA, independent chains) --
        f32x4 s[4];
        {
            __builtin_amdgcn_s_setprio(1);
#pragma unroll
            for (int g = 0; g < 4; ++g) {
                half8 kf0 = *(const half8*)(K + (size_t)(k0 + g * 16 + col) * 64 + u * 8);
                half8 kf1 = *(const half8*)(K + (size_t)(k0 + g * 16 + col) * 64 + 32 + u * 8);
                s[g] = __builtin_amdgcn_mfma_f32_16x16x32_f16(kf0, qf[0], zero4(), 0, 0, 0);
                s[g] = __builtin_amdgcn_mfma_f32_16x16x32_f16(kf1, qf[1], s[g], 0, 0, 0);
            }
            __builtin_amdgcn_s_setprio(0);
        }

        // ---- bias + mask (log2 domain) ----
#pragma unroll
        for (int g = 0; g < 4; ++g) {
            unsigned wsg = ((g < 2) ? wm0 : wm1) >> (((g & 1) * 16) + u4);
            int bb2 = bofs + k0 + g * 16;
#pragma unroll
            for (int r = 0; r < 4; ++r) {
                float x = fmaf(s[g][r], SC, bias_lds[bb2 + r]);
                s[g][r] = ((wsg >> r) & 1) ? x : -1e9f;
            }
        }

        // ---- online softmax (per q-col; values across lane quadrants) ------
        float tm = s[0][0];
#pragma unroll
        for (int g = 0; g < 4; ++g)
#pragma unroll
            for (int r = 0; r < 4; ++r) tm = fmaxf(tm, s[g][r]);
        tm = fmaxf(tm, __shfl_xor(tm, 16));
        tm = fmaxf(tm, __shfl_xor(tm, 32));
        float mnew = fmaxf(m, tm);
        float corr = EXP2F(m - mnew);
        m = mnew;
#pragma unroll
        for (int g = 0; g < 4; ++g)
#pragma unroll
            for (int r = 0; r < 4; ++r) s[g][r] = EXP2F(s[g][r] - m);
        float rs = 0.f;
#pragma unroll
        for (int g = 0; g < 4; ++g)
            rs += (s[g][0] + s[g][1]) + (s[g][2] + s[g][3]);
        rs += __shfl_xor(rs, 16);
        rs += __shfl_xor(rs, 32);
        l = l * corr + rs;
#pragma unroll
        for (int d = 0; d < 4; ++d)
#pragma unroll
            for (int r = 0; r < 4; ++r) acco[d][r] *= corr;

        // ---- P^T B-fragments via permlane swap + xor16 redistribution ------
        unsigned wA[4], wB[4];
#pragma unroll
        for (int g = 0; g < 4; ++g) {
            wA[g] = pkh(s[g][0], s[g][1]);
            wB[g] = pkh(s[g][2], s[g][3]);
        }
        bool ue = (u & 1) == 0;
        half8 pb[2];
#pragma unroll
        for (int c = 0; c < 2; ++c) {
            unsigned X = wA[2 * c], Y = wA[2 * c + 1];
            asm("v_permlane32_swap_b32 %0, %1" : "+v"(X), "+v"(Y));
            unsigned Xs = (unsigned)__shfl_xor((int)X, 16);
            unsigned Ys = (unsigned)__shfl_xor((int)Y, 16);
            unsigned XB = wB[2 * c], YB = wB[2 * c + 1];
            asm("v_permlane32_swap_b32 %0, %1" : "+v"(XB), "+v"(YB));
            unsigned XBs = (unsigned)__shfl_xor((int)XB, 16);
            unsigned YBs = (unsigned)__shfl_xor((int)YB, 16);
            unsigned d0 = ue ? X : Ys;
            unsigned d1 = ue ? XB : YBs;
            unsigned d2 = ue ? Xs : Y;
            unsigned d3 = ue ? XBs : YB;
            union { int4v i; half8 hf; } cv;
            cv.i = (int4v){(int)d0, (int)d1, (int)d2, (int)d3};
            pb[c] = cv.hf;
        }

        // ---- PV: O^T += V^T . P^T (4 dim-groups x 2 key-frags) -------------
        {
            __builtin_amdgcn_s_setprio(1);
#pragma unroll
            for (int d = 0; d < 4; ++d) {
                half8 vf0 = *(const half8*)(V + (size_t)(d * 16 + col) * TT + k0 + u * 8);
                half8 vf1 = *(const half8*)(V + (size_t)(d * 16 + col) * TT + k0 + 32 + u * 8);
                acco[d] = __builtin_amdgcn_mfma_f32_16x16x32_f16(vf0, pb[0], acco[d], 0, 0, 0);
                acco[d] = __builtin_amdgcn_mfma_f32_16x16x32_f16(vf1, pb[1], acco[d], 0, 0, 0);
            }
            __builtin_amdgcn_s_setprio(0);
        }
    }

    float inv = 1.f / l;
    _Float16* op = Oout + (bhoff * TT + q0 + col) * 64;
#pragma unroll
    for (int d = 0; d < 4; ++d) {
        half4 hv = {(_Float16)(acco[d][0] * inv), (_Float16)(acco[d][1] * inv),
                    (_Float16)(acco[d][2] * inv), (_Float16)(acco[d][3] * inv)};
        *(half4*)(op + d * 16 + u4) = hv;
    }
}

// ---------------- fc GEMM (dbuf 2-phase) + fused bias_write ------------------
__global__ __launch_bounds__(256) void fc_bias_kernel(
    const _Float16* __restrict__ O, const _Float16* __restrict__ Bt,
    float* __restrict__ out0, const float* __restrict__ btable,
    float* __restrict__ out1)
{
    __shared__ __align__(16) char lds[65536];
    int bid = blockIdx.x, tid = threadIdx.x;
    if (bid >= 256) {                      // ---- bias expansion ----
        const int n4 = HH * TT * TT / 4, stride = 2048 * 256;
        for (int i4 = (bid - 256) * 256 + tid; i4 < n4; i4 += stride) {
            int i = i4 * 4;
            int kk = i & (TT - 1);
            int qq = (i >> 11) & (TT - 1);
            int hh2 = i >> 22;
            const float* btp = btable + hh2 * NREL + (kk - qq + (TT - 1));
            float4 vv = make_float4(btp[0], btp[1], btp[2], btp[3]);
            reinterpret_cast<float4*>(out1)[i4] = vv;
        }
        return;
    }
    // ---- fc GEMM, 128x128 tile, dbuf gload_lds ----
    int bm = (bid & 31) * 128, bn = (bid >> 5) * 128;
    int wv = tid >> 6, lane = tid & 63, lo = lane & 31, hi = lane >> 5;
    int wr = wv >> 1, wc = wv & 1;
    int srow = wv * 32 + (lane >> 3);
    int scol = (lane & 7) * 8;
    int bb = bm >> 11, tbase = bm & (TT - 1);
    const _Float16* Abase = O + ((size_t)(bb * HH) * TT + tbase + srow) * 64 + scol;
    const _Float16* Bbase = Bt + (size_t)(bn + srow) * DMODEL + scol;

    f32x16 acc[2][2];
    acc[0][0] = zero16(); acc[0][1] = zero16();
    acc[1][0] = zero16(); acc[1][1] = zero16();

    auto stage = [&](int buf, int kt) {
#pragma unroll
        for (int t = 0; t < 4; ++t) {
            gload16(Abase + (size_t)kt * TT * 64 + (size_t)t * 8 * 64, lds + buf + wv * 4096 + t * 1024);
            gload16(Bbase + (size_t)t * 8 * DMODEL + kt * 64, lds + buf + 16384 + wv * 4096 + t * 1024);
        }
    };
    auto compute = [&](int buf) {
#pragma unroll
        for (int kk = 0; kk < 4; ++kk) {
            int cs = 2 * kk + hi;
            half8 a[2], b[2];
#pragma unroll
            for (int i = 0; i < 2; ++i) {
                a[i] = *(const half8*)(lds + buf + (wr * 64 + i * 32 + lo) * 128 + cs * 16);
                b[i] = *(const half8*)(lds + buf + 16384 + (wc * 64 + i * 32 + lo) * 128 + cs * 16);
            }
            acc[0][0] = __builtin_amdgcn_mfma_f32_32x32x16_f16(a[0], b[0], acc[0][0], 0, 0, 0);
            acc[0][1] = __builtin_amdgcn_mfma_f32_32x32x16_f16(a[0], b[1], acc[0][1], 0, 0, 0);
            acc[1][0] = __builtin_amdgcn_mfma_f32_32x32x16_f16(a[1], b[0], acc[1][0], 0, 0, 0);
            acc[1][1] = __builtin_amdgcn_mfma_f32_32x32x16_f16(a[1], b[1], acc[1][1], 0, 0, 0);
        }
    };

    stage(0, 0);
    __syncthreads();
    for (int kt = 0; kt < 16; kt += 2) {
        stage(32768, kt + 1);
        compute(0);
        __syncthreads();
        stage(0, kt + 2 < 16 ? kt + 2 : 15);
        compute(32768);
        __syncthreads();
    }

#pragma unroll
    for (int j = 0; j < 2; ++j) {
        int n = bn + wc * 64 + j * 32 + lo;
#pragma unroll
        for (int i = 0; i < 2; ++i) {
            int mb2 = bm + wr * 64 + i * 32 + 4 * hi;
#pragma unroll
            for (int r = 0; r < 16; ++r) {
                int m = mb2 + (r & 3) + 8 * (r >> 2);
                out0[(size_t)m * DMODEL + n] = acc[i][j][r];
            }
        }
    }
}

// ---------------------------------------------------------------------------
extern "C" void kernel_launch(void* const* d_in, const int* in_sizes, int n_in,
                              void* d_out, int out_size, void* d_ws, size_t ws_size,
                              hipStream_t stream) {
    const float* q        = (const float*)d_in[0];
    const float* k        = (const float*)d_in[1];
    const float* v        = (const float*)d_in[2];
    const int*   mask     = (const int*)  d_in[3];
    const float* Wq       = (const float*)d_in[4];
    const float* Wk       = (const float*)d_in[5];
    const float* Wv       = (const float*)d_in[6];
    const float* Wfc      = (const float*)d_in[7];
    const float* rel_bias = (const float*)d_in[8];

    float* out0 = (float*)d_out;                       // [B][T][1024]
    float* out1 = out0 + (size_t)BB * TT * DMODEL;     // [H][T][T]

    char* w = (char*)d_ws;
    _Float16* O   = (_Float16*)(w);                        // [0,8M)
    _Float16* qhf = (_Float16*)(w + ((size_t)24 << 20));
    _Float16* khf = (_Float16*)(w + ((size_t)32 << 20));
    _Float16* WT  = (_Float16*)(w + ((size_t)40 << 20));   // 4 x 2MB
    float*    btable = (float*)(w + ((size_t)48 << 20));
    unsigned* mbits  = (unsigned*)(w + ((size_t)48 << 20) + ((size_t)1 << 19));
    bool big = ws_size >= ((size_t)58 << 20);
    _Float16* vtf = big ? (_Float16*)(w + ((size_t)49 << 20) + ((size_t)1 << 19))
                        : (_Float16*)(w + ((size_t)8 << 20));  // fallback region

    prep_kernel<<<dim3(1280 + BB * TT * TT / 256), dim3(256), 0, stream>>>(
        mask, Wq, Wk, Wv, Wfc, rel_bias, WT, btable, mbits);

    if (big) {
        gemm_proj3<<<dim3(32, 8, 3), dim3(256), 0, stream>>>(q, k, v, WT,
                                                             qhf, khf, vtf, 0);
    } else {
        gemm_proj3<<<dim3(32, 8, 1), dim3(256), 0, stream>>>(q, k, v, WT, qhf, khf, vtf, 0);
        gemm_proj3<<<dim3(32, 8, 1), dim3(256), 0, stream>>>(q, k, v, WT, qhf, khf, vtf, 1);
        gemm_proj3<<<dim3(32, 8, 1), dim3(256), 0, stream>>>(q, k, v, WT, qhf, khf, vtf, 2);
    }

    attn_mfma16<<<dim3(BB * HH * 32), dim3(256), 0, stream>>>(
        qhf, khf, vtf, mbits, btable, O);

    fc_bias_kernel<<<dim3(2304), dim3(256), 0, stream>>>(
        O, WT + (size_t)3 * DMODEL * DMODEL, out0, btable, out1);
}

// Round 19
// 280.670 us; speedup vs baseline: 1.4451x; 1.4451x over previous
//
#include <hip/hip_runtime.h>
#include <math.h>

#define TT 2048
#define BB 2
#define HH 16
#define DMODEL 1024
#define NREL 4095                      // 2*TT-1

typedef __attribute__((ext_vector_type(8)))  _Float16 half8;
typedef __attribute__((ext_vector_type(4)))  _Float16 half4;
typedef __attribute__((ext_vector_type(16))) float    f32x16;
typedef __attribute__((ext_vector_type(4)))  int      int4v;

#define EXP2F(x) __builtin_amdgcn_exp2f(x)

__device__ __forceinline__ f32x16 zero16() {
    f32x16 v;
#pragma unroll
    for (int i = 0; i < 16; ++i) v[i] = 0.f;
    return v;
}

__device__ __forceinline__ unsigned pkh(float a, float b) {
    union { _Float16 h[2]; unsigned u; } x;
    x.h[0] = (_Float16)a; x.h[1] = (_Float16)b;
    return x.u;
}

// async global->LDS, 16B per lane; LDS dest = wave-uniform base + lane*16
__device__ __forceinline__ void gload16(const void* g, void* l) {
    __builtin_amdgcn_global_load_lds(
        (const __attribute__((address_space(1))) void*)g,
        (__attribute__((address_space(3))) void*)l, 16, 0, 0);
}

// ---------------- bucket (exact-integer replication of reference log math) ---
__device__ __forceinline__ int rel_bucket(int rel) {
    int base = rel > 0 ? 16 : 0;
    int r = rel < 0 ? -rel : rel;
    int lb;
    if (r < 8)       lb = r;
    else if (r < 12) lb = 8;
    else if (r < 16) lb = 9;
    else if (r < 23) lb = 10;
    else if (r < 32) lb = 11;
    else if (r < 46) lb = 12;
    else if (r < 64) lb = 13;
    else if (r < 91) lb = 14;
    else             lb = 15;
    return base + lb;
}

// ---------------- fused prep: bias_table | wtrans | cvt16 x3 | maskpack ------
__global__ __launch_bounds__(256) void prep_kernel(
    const float* __restrict__ q, const float* __restrict__ k,
    const float* __restrict__ v, const int* __restrict__ mask,
    const float* __restrict__ W0, const float* __restrict__ W1,
    const float* __restrict__ W2, const float* __restrict__ W3,
    const float* __restrict__ rel_bias,
    _Float16* __restrict__ q16, _Float16* __restrict__ k16,
    _Float16* __restrict__ v16, _Float16* __restrict__ WT,
    float* __restrict__ btable, unsigned* __restrict__ mb)
{
    __shared__ float t[64][65];
    int bid = blockIdx.x, tid = threadIdx.x;
    if (bid < 256) {
        int idx = bid * 256 + tid;
        if (idx < HH * NREL) {
            int h = idx / NREL, ri = idx % NREL;
            btable[idx] = rel_bias[rel_bucket(ri - (TT - 1)) * HH + h];
        }
    } else if (bid < 1280) {
        int zz = (bid - 256) >> 8, inner = (bid - 256) & 255;
        const float* src = zz == 0 ? W0 : zz == 1 ? W1 : zz == 2 ? W2 : W3;
        _Float16* dst = WT + (size_t)zz * DMODEL * DMODEL;
        int k0 = (inner >> 4) * 64, n0 = (inner & 15) * 64;
        int r = tid >> 4, c4 = (tid & 15) * 4;
#pragma unroll
        for (int i = 0; i < 4; ++i) {
            float4 vv = *(const float4*)(src + (size_t)(k0 + r + 16 * i) * DMODEL + n0 + c4);
            t[r + 16 * i][c4] = vv.x; t[r + 16 * i][c4 + 1] = vv.y;
            t[r + 16 * i][c4 + 2] = vv.z; t[r + 16 * i][c4 + 3] = vv.w;
        }
        __syncthreads();
        int rn = tid >> 2, ck = (tid & 3) * 16;
        half8 h0, h1;
#pragma unroll
        for (int j = 0; j < 8; ++j) h0[j] = (_Float16)t[ck + j][rn];
#pragma unroll
        for (int j = 0; j < 8; ++j) h1[j] = (_Float16)t[ck + 8 + j][rn];
        *(half8*)(dst + (size_t)(n0 + rn) * DMODEL + k0 + ck) = h0;
        *(half8*)(dst + (size_t)(n0 + rn) * DMODEL + k0 + ck + 8) = h1;
    } else if (bid < 7424) {
        int zz = (bid - 1280) >> 11, inner = (bid - 1280) & 2047;
        const float* src = zz == 0 ? q : zz == 1 ? k : v;
        _Float16* dst = zz == 0 ? q16 : zz == 1 ? k16 : v16;
        int i = inner * 256 + tid;
        const float4* in4 = (const float4*)src;
        float4 v0 = in4[(size_t)i * 2], v1 = in4[(size_t)i * 2 + 1];
        half8 h = {(_Float16)v0.x, (_Float16)v0.y, (_Float16)v0.z, (_Float16)v0.w,
                   (_Float16)v1.x, (_Float16)v1.y, (_Float16)v1.z, (_Float16)v1.w};
        *(half8*)(dst + (size_t)i * 8) = h;
    } else {
        int g = (bid - 7424) * 256 + tid;
        int vv = mask[g];
        unsigned long long bal = __ballot(vv != 0);
        if ((g & 63) == 0) {
            int word = g >> 5;
            mb[word]     = (unsigned)bal;
            mb[word + 1] = (unsigned)(bal >> 32);
        }
    }
}

// ---------------- fused projection MFMA GEMM (z: 0=q,1=k,2=v) ----------------
__global__ __launch_bounds__(256) void gemm_proj3(
    const _Float16* __restrict__ q16, const _Float16* __restrict__ k16,
    const _Float16* __restrict__ v16, const _Float16* __restrict__ WT,
    _Float16* __restrict__ qhf, _Float16* __restrict__ khf,
    _Float16* __restrict__ vtf, int zbase)
{
    __shared__ __align__(16) char lds[65536];   // 2 x {A [0,16K), B [16K,32K)}
    int z = zbase + blockIdx.z;
    const _Float16* A  = z == 0 ? q16 : z == 1 ? k16 : v16;
    const _Float16* Bt = WT + (size_t)z * DMODEL * DMODEL;
    int bm = blockIdx.x * 128, bn = blockIdx.y * 128;
    int tid = threadIdx.x;
    int wv = tid >> 6, lane = tid & 63, hi = lane >> 5;
    int lo = lane & 31;
    int wr = wv >> 1, wc = wv & 1;
    int srow = wv * 32 + (lane >> 3);
    int scol = (lane & 7) * 8;
    const _Float16* Abase = A  + (size_t)(bm + srow) * DMODEL + scol;
    const _Float16* Bbase = Bt + (size_t)(bn + srow) * DMODEL + scol;

    f32x16 acc[2][2];
    acc[0][0] = zero16(); acc[0][1] = zero16();
    acc[1][0] = zero16(); acc[1][1] = zero16();

    auto stage = [&](int buf, int kt) {
#pragma unroll
        for (int t = 0; t < 4; ++t) {
            gload16(Abase + (size_t)t * 8 * DMODEL + kt * 64, lds + buf + wv * 4096 + t * 1024);
            gload16(Bbase + (size_t)t * 8 * DMODEL + kt * 64, lds + buf + 16384 + wv * 4096 + t * 1024);
        }
    };
    auto compute = [&](int buf) {
#pragma unroll
        for (int kk = 0; kk < 4; ++kk) {
            int cs = 2 * kk + hi;
            half8 a[2], b[2];
#pragma unroll
            for (int i = 0; i < 2; ++i) {
                a[i] = *(const half8*)(lds + buf + (wr * 64 + i * 32 + lo) * 128 + cs * 16);
                b[i] = *(const half8*)(lds + buf + 16384 + (wc * 64 + i * 32 + lo) * 128 + cs * 16);
            }
            acc[0][0] = __builtin_amdgcn_mfma_f32_32x32x16_f16(a[0], b[0], acc[0][0], 0, 0, 0);
            acc[0][1] = __builtin_amdgcn_mfma_f32_32x32x16_f16(a[0], b[1], acc[0][1], 0, 0, 0);
            acc[1][0] = __builtin_amdgcn_mfma_f32_32x32x16_f16(a[1], b[0], acc[1][0], 0, 0, 0);
            acc[1][1] = __builtin_amdgcn_mfma_f32_32x32x16_f16(a[1], b[1], acc[1][1], 0, 0, 0);
        }
    };

    stage(0, 0);
    __syncthreads();
    for (int kt = 0; kt < 16; kt += 2) {
        stage(32768, kt + 1);
        compute(0);
        __syncthreads();
        stage(0, kt + 2 < 16 ? kt + 2 : 15);
        compute(32768);
        __syncthreads();
    }

    if (z < 2) {
        _Float16* C = z == 0 ? qhf : khf;
#pragma unroll
        for (int j = 0; j < 2; ++j) {
            int n = bn + wc * 64 + j * 32 + lo;
            int h = n >> 6, d = n & 63;
#pragma unroll
            for (int i = 0; i < 2; ++i) {
                int mb2 = bm + wr * 64 + i * 32 + 4 * hi;
#pragma unroll
                for (int r = 0; r < 16; ++r) {
                    int m = mb2 + (r & 3) + 8 * (r >> 2);
                    int b = m >> 11, t = m & (TT - 1);
                    C[((size_t)(b * HH + h) * TT + t) * 64 + d] = (_Float16)acc[i][j][r];
                }
            }
        }
    } else {
#pragma unroll
        for (int j = 0; j < 2; ++j) {
            int n = bn + wc * 64 + j * 32 + lo;
            int h = n >> 6, d = n & 63;
#pragma unroll
            for (int i = 0; i < 2; ++i) {
                int mb2 = bm + wr * 64 + i * 32 + 4 * hi;
                int b = mb2 >> 11, tb = mb2 & (TT - 1);
#pragma unroll
                for (int r4 = 0; r4 < 4; ++r4) {
                    half4 hv = {(_Float16)acc[i][j][4 * r4 + 0], (_Float16)acc[i][j][4 * r4 + 1],
                                (_Float16)acc[i][j][4 * r4 + 2], (_Float16)acc[i][j][4 * r4 + 3]};
                    *(half4*)(vtf + ((size_t)(b * HH + h) * 64 + d) * TT + tb + 8 * r4) = hv;
                }
            }
        }
    }
}

// ---------------- MFMA flash attention: Kc=128, log2-domain softmax ----------
__global__ __launch_bounds__(256) void attn_mfma(
    const _Float16* __restrict__ qh, const _Float16* __restrict__ kh,
    const _Float16* __restrict__ vt, const unsigned* __restrict__ maskbits,
    const float* __restrict__ btable, _Float16* __restrict__ Oout)
{
    __shared__ float bias_lds[4096];
    int bid = blockIdx.x;
    int xcd = bid & 7, j = bid >> 3;
    int qt = j & 15, bh = xcd + 8 * (j >> 4);
    int h = bh & 15, b = bh >> 4;
    int tid = threadIdx.x;
    int wv = tid >> 6, lane = tid & 63, lo = lane & 31, hi = lane >> 5;
    int q0 = qt * 128 + wv * 32;

    {   // stage this head's bias row into LDS, pre-scaled by log2(e)
        const float* bsrc = btable + h * NREL;
#pragma unroll
        for (int i = 0; i < 16; ++i) {
            int idx = i * 256 + tid;
            bias_lds[idx] = bsrc[idx < NREL ? idx : NREL - 1] * 1.44269504f;
        }
    }

    const size_t bhoff = (size_t)(b * HH + h);
    const _Float16* Q = qh + (bhoff * TT + q0) * 64;
    const _Float16* K = kh + bhoff * TT * 64;
    const _Float16* V = vt + bhoff * 64 * TT;

    half8 qf[4];
#pragma unroll
    for (int c = 0; c < 4; ++c)
        qf[c] = *(const half8*)(Q + (size_t)lo * 64 + c * 16 + hi * 8);

    const int bofs = (TT - 1) - (q0 + lo) + 4 * hi;
    const unsigned* mw = maskbits + ((size_t)b * TT + q0 + lo) * 64;
    const float SC = 0.125f * 1.44269504f;       // QK scale folded with log2(e)

    f32x16 acco0 = zero16(), acco1 = zero16();
    float m = -INFINITY, l = 0.f;

    __syncthreads();   // bias_lds ready

    for (int kt = 0; kt < 16; ++kt) {
        int k0 = kt * 128;
        unsigned wmA0 = mw[4 * kt], wmA1 = mw[4 * kt + 1];
        unsigned wmB0 = mw[4 * kt + 2], wmB1 = mw[4 * kt + 3];

        // ---- QK^T: 4 independent 32-key chains (128 keys) ----
        f32x16 sA0 = zero16(), sA1 = zero16(), sB0 = zero16(), sB1 = zero16();
        {
            half8 kf[4];
#pragma unroll
            for (int c = 0; c < 4; ++c)
                kf[c] = *(const half8*)(K + (size_t)(k0 + lo) * 64 + c * 16 + hi * 8);
            __builtin_amdgcn_s_setprio(1);
#pragma unroll
            for (int c = 0; c < 4; ++c)
                sA0 = __builtin_amdgcn_mfma_f32_32x32x16_f16(kf[c], qf[c], sA0, 0, 0, 0);
            __builtin_amdgcn_s_setprio(0);
#pragma unroll
            for (int c = 0; c < 4; ++c)
                kf[c] = *(const half8*)(K + (size_t)(k0 + 32 + lo) * 64 + c * 16 + hi * 8);
            __builtin_amdgcn_s_setprio(1);
#pragma unroll
            for (int c = 0; c < 4; ++c)
                sA1 = __builtin_amdgcn_mfma_f32_32x32x16_f16(kf[c], qf[c], sA1, 0, 0, 0);
            __builtin_amdgcn_s_setprio(0);
#pragma unroll
            for (int c = 0; c < 4; ++c)
                kf[c] = *(const half8*)(K + (size_t)(k0 + 64 + lo) * 64 + c * 16 + hi * 8);
            __builtin_amdgcn_s_setprio(1);
#pragma unroll
            for (int c = 0; c < 4; ++c)
                sB0 = __builtin_amdgcn_mfma_f32_32x32x16_f16(kf[c], qf[c], sB0, 0, 0, 0);
            __builtin_amdgcn_s_setprio(0);
#pragma unroll
            for (int c = 0; c < 4; ++c)
                kf[c] = *(const half8*)(K + (size_t)(k0 + 96 + lo) * 64 + c * 16 + hi * 8);
            __builtin_amdgcn_s_setprio(1);
#pragma unroll
            for (int c = 0; c < 4; ++c)
                sB1 = __builtin_amdgcn_mfma_f32_32x32x16_f16(kf[c], qf[c], sB1, 0, 0, 0);
            __builtin_amdgcn_s_setprio(0);
        }

        // ---- bias + mask (log2 domain) ----
        unsigned wsA0 = wmA0 >> (hi * 4), wsA1 = wmA1 >> (hi * 4);
        unsigned wsB0 = wmB0 >> (hi * 4), wsB1 = wmB1 >> (hi * 4);
        int bbase = bofs + k0;
#pragma unroll
        for (int r = 0; r < 16; ++r) {
            int sh = (r & 3) + 8 * (r >> 2);
            float a0 = fmaf(sA0[r], SC, bias_lds[bbase + sh]);
            float a1 = fmaf(sA1[r], SC, bias_lds[bbase + sh + 32]);
            float b0 = fmaf(sB0[r], SC, bias_lds[bbase + sh + 64]);
            float b1 = fmaf(sB1[r], SC, bias_lds[bbase + sh + 96]);
            sA0[r] = ((wsA0 >> sh) & 1) ? a0 : -1e9f;
            sA1[r] = ((wsA1 >> sh) & 1) ? a1 : -1e9f;
            sB0[r] = ((wsB0 >> sh) & 1) ? b0 : -1e9f;
            sB1[r] = ((wsB1 >> sh) & 1) ? b1 : -1e9f;
        }

        // ---- one softmax merge for all 128 keys ----
        float tr[8];
#pragma unroll
        for (int r = 0; r < 8; ++r) {
            float x0 = fmaxf(fmaxf(sA0[r], sA0[r + 8]), fmaxf(sA1[r], sA1[r + 8]));
            float x1 = fmaxf(fmaxf(sB0[r], sB0[r + 8]), fmaxf(sB1[r], sB1[r + 8]));
            tr[r] = fmaxf(x0, x1);
        }
#pragma unroll
        for (int r = 0; r < 4; ++r) tr[r] = fmaxf(tr[r], tr[r + 4]);
        float tm = fmaxf(fmaxf(tr[0], tr[1]), fmaxf(tr[2], tr[3]));
        tm = fmaxf(tm, __shfl_xor(tm, 32));
        float mnew = fmaxf(m, tm);
        float corr = EXP2F(m - mnew);
        m = mnew;

#pragma unroll
        for (int r = 0; r < 16; ++r) sA0[r] = EXP2F(sA0[r] - m);
#pragma unroll
        for (int r = 0; r < 16; ++r) sA1[r] = EXP2F(sA1[r] - m);
#pragma unroll
        for (int r = 0; r < 16; ++r) sB0[r] = EXP2F(sB0[r] - m);
#pragma unroll
        for (int r = 0; r < 16; ++r) sB1[r] = EXP2F(sB1[r] - m);
#pragma unroll
        for (int r = 0; r < 8; ++r)
            tr[r] = ((sA0[r] + sA0[r + 8]) + (sA1[r] + sA1[r + 8]))
                  + ((sB0[r] + sB0[r + 8]) + (sB1[r] + sB1[r + 8]));
#pragma unroll
        for (int r = 0; r < 4; ++r) tr[r] += tr[r + 4];
        float rs = (tr[0] + tr[1]) + (tr[2] + tr[3]);
        rs += __shfl_xor(rs, 32);
        l = l * corr + rs;
#pragma unroll
        for (int r = 0; r < 16; ++r) { acco0[r] *= corr; acco1[r] *= corr; }

        // ---- P^T fragments in-register (s-vectors die here) ----
        half8 pbA[4], pbB[4];
#pragma unroll
        for (int g = 0; g < 2; ++g)
#pragma unroll
            for (int hc = 0; hc < 2; ++hc) {
                int r0 = hc * 8;
                float p0 = g ? sA1[r0 + 0] : sA0[r0 + 0];
                float p1 = g ? sA1[r0 + 1] : sA0[r0 + 1];
                float p2 = g ? sA1[r0 + 2] : sA0[r0 + 2];
                float p3 = g ? sA1[r0 + 3] : sA0[r0 + 3];
                float p4 = g ? sA1[r0 + 4] : sA0[r0 + 4];
                float p5 = g ? sA1[r0 + 5] : sA0[r0 + 5];
                float p6 = g ? sA1[r0 + 6] : sA0[r0 + 6];
                float p7 = g ? sA1[r0 + 7] : sA0[r0 + 7];
                unsigned w0 = pkh(p0, p1);
                unsigned w2 = pkh(p4, p5);
                asm("v_permlane32_swap_b32 %0, %1" : "+v"(w0), "+v"(w2));
                unsigned w1 = pkh(p2, p3);
                unsigned w3 = pkh(p6, p7);
                asm("v_permlane32_swap_b32 %0, %1" : "+v"(w1), "+v"(w3));
                union { int4v i; half8 hf; } cv;
                cv.i = (int4v){(int)w0, (int)w1, (int)w2, (int)w3};
                pbA[2 * g + hc] = cv.hf;
            }
#pragma unroll
        for (int g = 0; g < 2; ++g)
#pragma unroll
            for (int hc = 0; hc < 2; ++hc) {
                int r0 = hc * 8;
                float p0 = g ? sB1[r0 + 0] : sB0[r0 + 0];
                float p1 = g ? sB1[r0 + 1] : sB0[r0 + 1];
                float p2 = g ? sB1[r0 + 2] : sB0[r0 + 2];
                float p3 = g ? sB1[r0 + 3] : sB0[r0 + 3];
                float p4 = g ? sB1[r0 + 4] : sB0[r0 + 4];
                float p5 = g ? sB1[r0 + 5] : sB0[r0 + 5];
                float p6 = g ? sB1[r0 + 6] : sB0[r0 + 6];
                float p7 = g ? sB1[r0 + 7] : sB0[r0 + 7];
                unsigned w0 = pkh(p0, p1);
                unsigned w2 = pkh(p4, p5);
                asm("v_permlane32_swap_b32 %0, %1" : "+v"(w0), "+v"(w2));
                unsigned w1 = pkh(p2, p3);
                unsigned w3 = pkh(p6, p7);
                asm("v_permlane32_swap_b32 %0, %1" : "+v"(w1), "+v"(w3));
                union { int4v i; half8 hf; } cv;
                cv.i = (int4v){(int)w0, (int)w1, (int)w2, (int)w3};
                pbB[2 * g + hc] = cv.hf;
            }

        // ---- PV: 4 V-load groups, 16 MFMA ----
        {
            half8 vf[4];
#pragma unroll
            for (int c = 0; c < 4; ++c)
                vf[c] = *(const half8*)(V + (size_t)lo * TT + k0 + c * 16 + hi * 8);
            __builtin_amdgcn_s_setprio(1);
#pragma unroll
            for (int c = 0; c < 4; ++c)
                acco0 = __builtin_amdgcn_mfma_f32_32x32x16_f16(vf[c], pbA[c], acco0, 0, 0, 0);
            __builtin_amdgcn_s_setprio(0);
#pragma unroll
            for (int c = 0; c < 4; ++c)
                vf[c] = *(const half8*)(V + (size_t)lo * TT + k0 + 64 + c * 16 + hi * 8);
            __builtin_amdgcn_s_setprio(1);
#pragma unroll
            for (int c = 0; c < 4; ++c)
                acco0 = __builtin_amdgcn_mfma_f32_32x32x16_f16(vf[c], pbB[c], acco0, 0, 0, 0);
            __builtin_amdgcn_s_setprio(0);
#pragma unroll
            for (int c = 0; c < 4; ++c)
                vf[c] = *(const half8*)(V + (size_t)(32 + lo) * TT + k0 + c * 16 + hi * 8);
            __builtin_amdgcn_s_setprio(1);
#pragma unroll
            for (int c = 0; c < 4; ++c)
                acco1 = __builtin_amdgcn_mfma_f32_32x32x16_f16(vf[c], pbA[c], acco1, 0, 0, 0);
            __builtin_amdgcn_s_setprio(0);
#pragma unroll
            for (int c = 0; c < 4; ++c)
                vf[c] = *(const half8*)(V + (size_t)(32 + lo) * TT + k0 + 64 + c * 16 + hi * 8);
            __builtin_amdgcn_s_setprio(1);
#pragma unroll
            for (int c = 0; c < 4; ++c)
                acco1 = __builtin_amdgcn_mfma_f32_32x32x16_f16(vf[c], pbB[c], acco1, 0, 0, 0);
            __builtin_amdgcn_s_setprio(0);
        }
    }

    float inv = 1.f / l;
    _Float16* op = Oout + (bhoff * TT + q0 + lo) * 64;
#pragma unroll
    for (int r4 = 0; r4 < 4; ++r4) {
        int d0 = 8 * r4 + 4 * hi;
        half4 h0 = {(_Float16)(acco0[4 * r4 + 0] * inv), (_Float16)(acco0[4 * r4 + 1] * inv),
                    (_Float16)(acco0[4 * r4 + 2] * inv), (_Float16)(acco0[4 * r4 + 3] * inv)};
        *(half4*)(op + d0) = h0;
        half4 h1 = {(_Float16)(acco1[4 * r4 + 0] * inv), (_Float16)(acco1[4 * r4 + 1] * inv),
                    (_Float16)(acco1[4 * r4 + 2] * inv), (_Float16)(acco1[4 * r4 + 3] * inv)};
        *(half4*)(op + d0 + 32) = h1;
    }
}

// ---------------- fc GEMM (dbuf 2-phase) + fused bias_write ------------------
__global__ __launch_bounds__(256) void fc_bias_kernel(
    const _Float16* __restrict__ O, const _Float16* __restrict__ Bt,
    float* __restrict__ out0, const float* __restrict__ btable,
    float* __restrict__ out1)
{
    __shared__ __align__(16) char lds[65536];
    int bid = blockIdx.x, tid = threadIdx.x;
    if (bid >= 256) {                      // ---- bias expansion ----
        const int n4 = HH * TT * TT / 4, stride = 2048 * 256;
        for (int i4 = (bid - 256) * 256 + tid; i4 < n4; i4 += stride) {
            int i = i4 * 4;
            int kk = i & (TT - 1);
            int qq = (i >> 11) & (TT - 1);
            int hh2 = i >> 22;
            const float* btp = btable + hh2 * NREL + (kk - qq + (TT - 1));
            float4 vv = make_float4(btp[0], btp[1], btp[2], btp[3]);
            reinterpret_cast<float4*>(out1)[i4] = vv;
        }
        return;
    }
    // ---- fc GEMM, 128x128 tile, dbuf gload_lds ----
    int bm = (bid & 31) * 128, bn = (bid >> 5) * 128;
    int wv = tid >> 6, lane = tid & 63, lo = lane & 31, hi = lane >> 5;
    int wr = wv >> 1, wc = wv & 1;
    int srow = wv * 32 + (lane >> 3);
    int scol = (lane & 7) * 8;
    int bb = bm >> 11, tbase = bm & (TT - 1);
    const _Float16* Abase = O + ((size_t)(bb * HH) * TT + tbase + srow) * 64 + scol;
    const _Float16* Bbase = Bt + (size_t)(bn + srow) * DMODEL + scol;

    f32x16 acc[2][2];
    acc[0][0] = zero16(); acc[0][1] = zero16();
    acc[1][0] = zero16(); acc[1][1] = zero16();

    auto stage = [&](int buf, int kt) {
#pragma unroll
        for (int t = 0; t < 4; ++t) {
            gload16(Abase + (size_t)kt * TT * 64 + (size_t)t * 8 * 64, lds + buf + wv * 4096 + t * 1024);
            gload16(Bbase + (size_t)t * 8 * DMODEL + kt * 64, lds + buf + 16384 + wv * 4096 + t * 1024);
        }
    };
    auto compute = [&](int buf) {
#pragma unroll
        for (int kk = 0; kk < 4; ++kk) {
            int cs = 2 * kk + hi;
            half8 a[2], b[2];
#pragma unroll
            for (int i = 0; i < 2; ++i) {
                a[i] = *(const half8*)(lds + buf + (wr * 64 + i * 32 + lo) * 128 + cs * 16);
                b[i] = *(const half8*)(lds + buf + 16384 + (wc * 64 + i * 32 + lo) * 128 + cs * 16);
            }
            acc[0][0] = __builtin_amdgcn_mfma_f32_32x32x16_f16(a[0], b[0], acc[0][0], 0, 0, 0);
            acc[0][1] = __builtin_amdgcn_mfma_f32_32x32x16_f16(a[0], b[1], acc[0][1], 0, 0, 0);
            acc[1][0] = __builtin_amdgcn_mfma_f32_32x32x16_f16(a[1], b[0], acc[1][0], 0, 0, 0);
            acc[1][1] = __builtin_amdgcn_mfma_f32_32x32x16_f16(a[1], b[1], acc[1][1], 0, 0, 0);
        }
    };

    stage(0, 0);
    __syncthreads();
    for (int kt = 0; kt < 16; kt += 2) {
        stage(32768, kt + 1);
        compute(0);
        __syncthreads();
        stage(0, kt + 2 < 16 ? kt + 2 : 15);
        compute(32768);
        __syncthreads();
    }

#pragma unroll
    for (int j = 0; j < 2; ++j) {
        int n = bn + wc * 64 + j * 32 + lo;
#pragma unroll
        for (int i = 0; i < 2; ++i) {
            int mb2 = bm + wr * 64 + i * 32 + 4 * hi;
#pragma unroll
            for (int r = 0; r < 16; ++r) {
                int m = mb2 + (r & 3) + 8 * (r >> 2);
                out0[(size_t)m * DMODEL + n] = acc[i][j][r];
            }
        }
    }
}

// ---------------------------------------------------------------------------
extern "C" void kernel_launch(void* const* d_in, const int* in_sizes, int n_in,
                              void* d_out, int out_size, void* d_ws, size_t ws_size,
                              hipStream_t stream) {
    const float* q        = (const float*)d_in[0];
    const float* k        = (const float*)d_in[1];
    const float* v        = (const float*)d_in[2];
    const int*   mask     = (const int*)  d_in[3];
    const float* Wq       = (const float*)d_in[4];
    const float* Wk       = (const float*)d_in[5];
    const float* Wv       = (const float*)d_in[6];
    const float* Wfc      = (const float*)d_in[7];
    const float* rel_bias = (const float*)d_in[8];

    float* out0 = (float*)d_out;                       // [B][T][1024]
    float* out1 = out0 + (size_t)BB * TT * DMODEL;     // [H][T][T]

    char* w = (char*)d_ws;
    _Float16* q16 = (_Float16*)(w);
    _Float16* k16 = (_Float16*)(w + ((size_t)8  << 20));
    _Float16* v16 = (_Float16*)(w + ((size_t)16 << 20));   // dead after proj3 -> O
    _Float16* qhf = (_Float16*)(w + ((size_t)24 << 20));
    _Float16* khf = (_Float16*)(w + ((size_t)32 << 20));
    _Float16* WT  = (_Float16*)(w + ((size_t)40 << 20));   // 4 x 2MB
    float*    btable = (float*)(w + ((size_t)48 << 20));
    unsigned* mbits  = (unsigned*)(w + ((size_t)48 << 20) + ((size_t)1 << 19));
    bool big = ws_size >= ((size_t)58 << 20);
    _Float16* vtf = big ? (_Float16*)(w + ((size_t)49 << 20) + ((size_t)1 << 19))
                        : k16;                             // fallback: alias k16
    _Float16* O = v16;

    prep_kernel<<<dim3(40192), dim3(256), 0, stream>>>(
        q, k, v, mask, Wq, Wk, Wv, Wfc, rel_bias, q16, k16, v16, WT, btable, mbits);

    if (big) {
        gemm_proj3<<<dim3(32, 8, 3), dim3(256), 0, stream>>>(q16, k16, v16, WT,
                                                             qhf, khf, vtf, 0);
    } else {
        gemm_proj3<<<dim3(32, 8, 1), dim3(256), 0, stream>>>(q16, k16, v16, WT, qhf, khf, vtf, 0);
        gemm_proj3<<<dim3(32, 8, 1), dim3(256), 0, stream>>>(q16, k16, v16, WT, qhf, khf, vtf, 1);
        gemm_proj3<<<dim3(32, 8, 1), dim3(256), 0, stream>>>(q16, k16, v16, WT, qhf, khf, vtf, 2);
    }

    attn_mfma<<<dim3(BB * HH * 16), dim3(256), 0, stream>>>(
        qhf, khf, vtf, mbits, btable, O);

    fc_bias_kernel<<<dim3(2304), dim3(256), 0, stream>>>(
        O, WT + (size_t)3 * DMODEL * DMODEL, out0, btable, out1);
}